// Round 9
// baseline (185.897 us; speedup 1.0000x reference)
//
#include <hip/hip_runtime.h>

#define HH 383
#define WW 383
#define CINC 64
#define COUTC 128
#define HO 191
#define WO 191
#define MIDN (4L * HO * WO * COUTC)   // 18,690,048 elements
#define NIDX (4 * HH * WW)            // 586,756 pixels

typedef __attribute__((ext_vector_type(8))) short short8;
typedef __attribute__((ext_vector_type(8))) unsigned short ushort8;
typedef __attribute__((ext_vector_type(4))) float f32x4;

static __device__ inline unsigned short f2bf(float f) {
    unsigned u = __float_as_uint(f);
    unsigned r = (u + 0x7FFFu + ((u >> 16) & 1u)) >> 16;
    return (unsigned short)r;
}

// ---------------- prep: pack W1/W2 frags, feats->bf16 compact, zero row, counters, idx=-1 ----------
__global__ void prep(const float* __restrict__ feats,
                     const float* __restrict__ W1, const float* __restrict__ W2,
                     unsigned short* __restrict__ featsB,
                     unsigned short* __restrict__ W1p, unsigned short* __restrict__ W2p,
                     unsigned short* __restrict__ zrow, int* __restrict__ cnt,
                     int* __restrict__ idx, int npts) {
    int t = blockIdx.x * blockDim.x + threadIdx.x;
    int N = gridDim.x * blockDim.x;
    if (t < 73728) {
        // W1p[((tap*2+kc)*8+ng)*512 + l*8 + j] = W1[(tap*64 + kc*32+(l>>4)*8+j)*128 + ng*16+(l&15)]
        int j  = t & 7;
        int l  = (t >> 3) & 63;
        int ng = (t >> 9) & 7;
        int tk = t >> 12;
        int tap = tk >> 1, kc = tk & 1;
        int ci = kc * 32 + (l >> 4) * 8 + j;
        int co = ng * 16 + (l & 15);
        W1p[t] = f2bf(W1[(tap * 64 + ci) * 128 + co]);
        // W2p[((tap*4+kc)*4+ng)*512 + l*8 + j] = W2[(tap*128 + kc*32+(l>>4)*8+j)*64 + ng*16+(l&15)]
        int ng2  = (t >> 9) & 3;
        int kc2  = (t >> 11) & 3;
        int tap2 = t >> 13;
        int m = kc2 * 32 + (l >> 4) * 8 + j;
        int c = ng2 * 16 + (l & 15);
        W2p[t] = f2bf(W2[(tap2 * 128 + m) * 64 + c]);
    }
    if (t < 128) zrow[t] = 0;
    if (t < 4) cnt[t] = 0;
    for (int i = t; i < NIDX; i += N) idx[i] = -1;
    if (t < (npts + 1) * 8) {
        int p = t >> 3, q = t & 7;
        ushort8 v = {0, 0, 0, 0, 0, 0, 0, 0};
        if (p < npts) {
            const float* f = feats + (long)p * 64 + q * 8;
            #pragma unroll
            for (int k = 0; k < 8; ++k) v[k] = f2bf(f[k]);
        }
        *(ushort8*)&featsB[(long)p * 64 + q * 8] = v;
    }
}

// ---------------- classify: parity groups (wave-aggregated atomics) + pixel->point map ----------------
__global__ void classify(const int* __restrict__ coors, int npts,
                         int* __restrict__ grp, int* __restrict__ cnt,
                         int* __restrict__ idx) {
    int t = blockIdx.x * blockDim.x + threadIdx.x;
    int lane = threadIdx.x & 63;
    int g = -1;
    if (t < npts) {
        int b = coors[3 * t], y = coors[3 * t + 1], x = coors[3 * t + 2];
        g = (y & 1) * 2 + (x & 1);
        idx[(b * HH + y) * WW + x] = t;
    }
    #pragma unroll
    for (int gg = 0; gg < 4; ++gg) {
        unsigned long long mask = __ballot(g == gg);
        if (!mask) continue;
        int leader = __ffsll((long long)mask) - 1;
        int base = 0;
        if (lane == leader) base = atomicAdd(&cnt[gg], __popcll(mask));
        base = __shfl(base, leader);
        if (g == gg) {
            int rank = __popcll(mask & ((1ULL << lane) - 1ULL));
            grp[gg * npts + base + rank] = t;
        }
    }
}

// ---------------- conv1: 3x3 stride-2 VALID, LDS-free gather MFMA implicit GEMM ----------------
// block: 64 j x 128 co; wave w: j-half jw=(w&1)*32 (32 positions), co-half (w>>1)*64.
// Per tap: 2 idx lookups + 4 A-gathers (16B/lane from featsB) + 8 B-loads + 16 MFMA.
__global__ __launch_bounds__(256, 4) void conv1_mfma(const unsigned short* __restrict__ featsB,
                                                     const int* __restrict__ idxm,
                                                     const unsigned short* __restrict__ W1p,
                                                     unsigned short* __restrict__ mid, int npts) {
    const int j0 = blockIdx.x * 64;
    const int i  = blockIdx.y;
    const int b  = blockIdx.z;
    const int tid = threadIdx.x;
    const int w = tid >> 6, l = tid & 63;
    const int jw = (w & 1) * 32;
    const int ngb = (w >> 1) * 4;      // co half: ng base
    const int hi8 = (l >> 4) * 8;
    const int jl = l & 15;
    const int jbase = j0 + jw + jl;

    f32x4 zf = {0.f, 0.f, 0.f, 0.f};
    f32x4 acc[2][4];
    #pragma unroll
    for (int mt = 0; mt < 2; ++mt)
        #pragma unroll
        for (int ng = 0; ng < 4; ++ng) acc[mt][ng] = zf;

    #pragma unroll
    for (int ky = 0; ky < 3; ++ky) {
        const int rowb = (b * HH + 2 * i + ky) * WW;
        #pragma unroll
        for (int kx = 0; kx < 3; ++kx) {
            const int tap = ky * 3 + kx;
            long ro[2];
            #pragma unroll
            for (int mt = 0; mt < 2; ++mt) {
                int j = jbase + mt * 16;
                int id = -1;
                if (j < WO) id = idxm[rowb + 2 * j + kx];
                ro[mt] = (long)(id >= 0 ? id : npts) * 64;
            }
            #pragma unroll
            for (int kc = 0; kc < 2; ++kc) {
                const unsigned short* wp = &W1p[(((tap * 2 + kc) * 8 + ngb) << 9) + l * 8];
                short8 b0 = *(const short8*)&wp[0];
                short8 b1 = *(const short8*)&wp[512];
                short8 b2 = *(const short8*)&wp[1024];
                short8 b3 = *(const short8*)&wp[1536];
                #pragma unroll
                for (int mt = 0; mt < 2; ++mt) {
                    short8 a = *(const short8*)&featsB[ro[mt] + kc * 32 + hi8];
                    acc[mt][0] = __builtin_amdgcn_mfma_f32_16x16x32_bf16(a, b0, acc[mt][0], 0, 0, 0);
                    acc[mt][1] = __builtin_amdgcn_mfma_f32_16x16x32_bf16(a, b1, acc[mt][1], 0, 0, 0);
                    acc[mt][2] = __builtin_amdgcn_mfma_f32_16x16x32_bf16(a, b2, acc[mt][2], 0, 0, 0);
                    acc[mt][3] = __builtin_amdgcn_mfma_f32_16x16x32_bf16(a, b3, acc[mt][3], 0, 0, 0);
                }
            }
        }
    }

    // epilogue: D col = l&15 -> co offset; row = (l>>4)*4+reg -> j offset
    #pragma unroll
    for (int mt = 0; mt < 2; ++mt) {
        #pragma unroll
        for (int reg = 0; reg < 4; ++reg) {
            int j = j0 + jw + mt * 16 + (l >> 4) * 4 + reg;
            if (j < WO) {
                long base = (((long)b * HO + i) * WO + j) * COUTC + ngb * 16 + jl;
                #pragma unroll
                for (int ng = 0; ng < 4; ++ng)
                    mid[base + ng * 16] = f2bf(acc[mt][ng][reg]);
            }
        }
    }
}

// ---------------- conv2: parity-grouped masked deconv via bf16 MFMA gather-GEMM ----------------
// block = 128 points x 64 co, 4 waves; wave w: points [32w, 32w+32), all 64 co (2 m-frags).
__global__ __launch_bounds__(256, 4) void conv2_mfma(const unsigned short* __restrict__ mid,
                                                     const unsigned short* __restrict__ W2p,
                                                     const int* __restrict__ coors,
                                                     const int* __restrict__ grp,
                                                     const int* __restrict__ cnt,
                                                     float* __restrict__ res, int npts) {
    __shared__ int meta[128 * 4];

    const int g  = blockIdx.y;
    const int n  = cnt[g];
    const int p0 = blockIdx.x * 128;
    if (p0 >= n) return;
    const int gy = g >> 1, gx = g & 1;
    const int tid = threadIdx.x, l = tid & 63, w = tid >> 6;

    if (tid < 128) {
        int pp = p0 + tid;
        if (pp < n) {
            int t = grp[g * npts + pp];
            meta[tid * 4 + 0] = coors[3 * t + 0];
            meta[tid * 4 + 1] = coors[3 * t + 1];
            meta[tid * 4 + 2] = coors[3 * t + 2];
            meta[tid * 4 + 3] = t;
        } else {
            meta[tid * 4 + 1] = -1;
        }
    }
    __syncthreads();

    const int pbase = w * 32;
    const int hi8 = (l >> 4) * 8;
    int bA[2], yA[2], xA[2];
    #pragma unroll
    for (int mt = 0; mt < 2; ++mt) {
        int pA = pbase + mt * 16 + (l & 15);
        bA[mt] = meta[pA * 4 + 0];
        yA[mt] = meta[pA * 4 + 1];
        xA[mt] = meta[pA * 4 + 2];
    }

    f32x4 zf = {0.f, 0.f, 0.f, 0.f};
    f32x4 acc[2][4];
    #pragma unroll
    for (int mt = 0; mt < 2; ++mt)
        #pragma unroll
        for (int ng = 0; ng < 4; ++ng) acc[mt][ng] = zf;

    const int nsy = gy ? 1 : 2, nsx = gx ? 1 : 2;
    for (int sy = 0; sy < nsy; ++sy) {
        const int ky = gy ? 1 : sy * 2;
        for (int sx = 0; sx < nsx; ++sx) {
            const int kx = gx ? 1 : sx * 2;
            const int tap = ky * 3 + kx;
            long off[2];
            #pragma unroll
            for (int mt = 0; mt < 2; ++mt) {
                int i = gy ? (yA[mt] >> 1) : ((yA[mt] >> 1) - 1 + sy);
                int j = gx ? (xA[mt] >> 1) : ((xA[mt] >> 1) - 1 + sx);
                bool ok = (yA[mt] >= 0) && (unsigned)i < (unsigned)HO && (unsigned)j < (unsigned)WO;
                off[mt] = ok ? ((long)(bA[mt] * HO + i) * WO + j) * COUTC : MIDN;
            }

            #pragma unroll
            for (int kc = 0; kc < 4; ++kc) {
                short8 a0 = *(const short8*)&mid[off[0] + kc * 32 + hi8];
                short8 a1 = *(const short8*)&mid[off[1] + kc * 32 + hi8];
                const unsigned short* wp = &W2p[((tap * 4 + kc) * 4) * 512 + l * 8];
                short8 b0 = *(const short8*)&wp[0];
                short8 b1 = *(const short8*)&wp[512];
                short8 b2 = *(const short8*)&wp[1024];
                short8 b3 = *(const short8*)&wp[1536];
                acc[0][0] = __builtin_amdgcn_mfma_f32_16x16x32_bf16(a0, b0, acc[0][0], 0, 0, 0);
                acc[0][1] = __builtin_amdgcn_mfma_f32_16x16x32_bf16(a0, b1, acc[0][1], 0, 0, 0);
                acc[0][2] = __builtin_amdgcn_mfma_f32_16x16x32_bf16(a0, b2, acc[0][2], 0, 0, 0);
                acc[0][3] = __builtin_amdgcn_mfma_f32_16x16x32_bf16(a0, b3, acc[0][3], 0, 0, 0);
                acc[1][0] = __builtin_amdgcn_mfma_f32_16x16x32_bf16(a1, b0, acc[1][0], 0, 0, 0);
                acc[1][1] = __builtin_amdgcn_mfma_f32_16x16x32_bf16(a1, b1, acc[1][1], 0, 0, 0);
                acc[1][2] = __builtin_amdgcn_mfma_f32_16x16x32_bf16(a1, b2, acc[1][2], 0, 0, 0);
                acc[1][3] = __builtin_amdgcn_mfma_f32_16x16x32_bf16(a1, b3, acc[1][3], 0, 0, 0);
            }
        }
    }

    #pragma unroll
    for (int mt = 0; mt < 2; ++mt) {
        #pragma unroll
        for (int reg = 0; reg < 4; ++reg) {
            int pl = pbase + mt * 16 + (l >> 4) * 4 + reg;
            if (meta[pl * 4 + 1] >= 0) {
                int pt = meta[pl * 4 + 3];
                float* rp = &res[(long)pt * 64 + (l & 15)];
                #pragma unroll
                for (int ng = 0; ng < 4; ++ng) rp[ng * 16] = acc[mt][ng][reg];
            }
        }
    }
}

// ---------------- expand: compact res + idx map -> dense NCHW output (coalesced) ----------------
__global__ __launch_bounds__(256) void expand(const float4* __restrict__ res4,
                                              const int* __restrict__ idx,
                                              float* __restrict__ out) {
    const int y = blockIdx.x, b = blockIdx.y;
    const int tid = threadIdx.x;
    const long plane = (long)HH * WW;
    const int rbase = (b * HH + y) * WW;

    #pragma unroll
    for (int half = 0; half < 2; ++half) {
        int x = half * 256 + tid;
        if (x < WW) {
            int id = idx[rbase + x];
            long obase = (long)b * 64 * plane + (long)y * WW + x;
            #pragma unroll 4
            for (int c4 = 0; c4 < 16; ++c4) {
                float4 v = make_float4(0.f, 0.f, 0.f, 0.f);
                if (id >= 0) v = res4[(long)id * 16 + c4];
                out[obase + (c4 * 4 + 0) * plane] = v.x;
                out[obase + (c4 * 4 + 1) * plane] = v.y;
                out[obase + (c4 * 4 + 2) * plane] = v.z;
                out[obase + (c4 * 4 + 3) * plane] = v.w;
            }
        }
    }
}

extern "C" void kernel_launch(void* const* d_in, const int* in_sizes, int n_in,
                              void* d_out, int out_size, void* d_ws, size_t ws_size,
                              hipStream_t stream) {
    const float* feats = (const float*)d_in[0];
    const int* coors = (const int*)d_in[1];
    const float* W1 = (const float*)d_in[3];
    const float* W2 = (const float*)d_in[4];
    float* out = (float*)d_out;
    int npts = in_sizes[1] / 3;

    // d_ws layout:
    //   midB   MIDN ushorts          (37,380,096 B)
    //   zrowB  128 ushorts           (safe row for conv2 A-gather, adjacent to mid)
    //   W1p    73728 ushorts
    //   W2p    73728 ushorts
    //   cnt    4 ints
    //   grp    4*npts ints
    //   idx    NIDX ints
    //   res    npts*64 floats
    //   featsB (npts+1)*64 ushorts   (zero row at index npts)
    char* wsb = (char*)d_ws;
    unsigned short* midB  = (unsigned short*)wsb;
    unsigned short* zrowB = midB + MIDN;
    unsigned short* W1p   = zrowB + 128;
    unsigned short* W2p   = W1p + 73728;
    int* cnt = (int*)(W2p + 73728);
    int* grp = cnt + 4;
    int* idx = grp + 4 * npts;
    float* res = (float*)(idx + NIDX);
    unsigned short* featsB = (unsigned short*)(res + (size_t)npts * 64);

    // 1) fused prep
    int pthreads = (npts + 1) * 8;
    prep<<<(pthreads + 255) / 256, 256, 0, stream>>>(feats, W1, W2, featsB, W1p, W2p,
                                                     zrowB, cnt, idx, npts);

    // 2) classify: parity groups + pixel->point map
    classify<<<(npts + 255) / 256, 256, 0, stream>>>(coors, npts, grp, cnt, idx);

    // 3) conv1 via LDS-free gather MFMA -> mid bf16
    conv1_mfma<<<dim3(3, HO, 4), 256, 0, stream>>>(featsB, idx, W1p, midB, npts);

    // 4) conv2 via MFMA -> compact res (indexed by original point id)
    int pblocks = (npts + 127) / 128;
    conv2_mfma<<<dim3(pblocks, 4), 256, 0, stream>>>(midB, W2p, coors, grp, cnt, res, npts);

    // 5) expand compact res to dense NCHW output (writes every element)
    expand<<<dim3(HH, 4), 256, 0, stream>>>((const float4*)res, idx, out);
}

// Round 10
// 175.592 us; speedup vs baseline: 1.0587x; 1.0587x over previous
//
#include <hip/hip_runtime.h>

#define HH 383
#define WW 383
#define CINC 64
#define COUTC 128
#define HO 191
#define WO 191
#define MIDN (4L * HO * WO * COUTC)   // 18,690,048 elements
#define NIDX (4 * HH * WW)            // 586,756 pixels

typedef __attribute__((ext_vector_type(8))) short short8;
typedef __attribute__((ext_vector_type(8))) unsigned short ushort8;
typedef __attribute__((ext_vector_type(4))) float f32x4;

static __device__ inline unsigned short f2bf(float f) {
    unsigned u = __float_as_uint(f);
    unsigned r = (u + 0x7FFFu + ((u >> 16) & 1u)) >> 16;
    return (unsigned short)r;
}

// ---------------- prep: pack W1/W2 frags, feats->bf16 compact, zero row, counters, idx=-1 ----------
__global__ void prep(const float* __restrict__ feats,
                     const float* __restrict__ W1, const float* __restrict__ W2,
                     unsigned short* __restrict__ featsB,
                     unsigned short* __restrict__ W1p, unsigned short* __restrict__ W2p,
                     unsigned short* __restrict__ zrow, int* __restrict__ cnt,
                     int* __restrict__ idx, int npts) {
    int t = blockIdx.x * blockDim.x + threadIdx.x;
    int N = gridDim.x * blockDim.x;
    if (t < 73728) {
        // W1p[((tap*2+kc)*8+ng)*512 + l*8 + j] = W1[(tap*64 + kc*32+(l>>4)*8+j)*128 + ng*16+(l&15)]
        int j  = t & 7;
        int l  = (t >> 3) & 63;
        int ng = (t >> 9) & 7;
        int tk = t >> 12;
        int tap = tk >> 1, kc = tk & 1;
        int ci = kc * 32 + (l >> 4) * 8 + j;
        int co = ng * 16 + (l & 15);
        W1p[t] = f2bf(W1[(tap * 64 + ci) * 128 + co]);
        // W2p[((tap*4+kc)*4+ng)*512 + l*8 + j] = W2[(tap*128 + kc*32+(l>>4)*8+j)*64 + ng*16+(l&15)]
        int ng2  = (t >> 9) & 3;
        int kc2  = (t >> 11) & 3;
        int tap2 = t >> 13;
        int m = kc2 * 32 + (l >> 4) * 8 + j;
        int c = ng2 * 16 + (l & 15);
        W2p[t] = f2bf(W2[(tap2 * 128 + m) * 64 + c]);
    }
    if (t < 128) zrow[t] = 0;
    if (t < 4) cnt[t] = 0;
    for (int i = t; i < NIDX; i += N) idx[i] = -1;
    if (t < (npts + 1) * 8) {
        int p = t >> 3, q = t & 7;
        ushort8 v = {0, 0, 0, 0, 0, 0, 0, 0};
        if (p < npts) {
            const float* f = feats + (long)p * 64 + q * 8;
            #pragma unroll
            for (int k = 0; k < 8; ++k) v[k] = f2bf(f[k]);
        }
        *(ushort8*)&featsB[(long)p * 64 + q * 8] = v;
    }
}

// ---------------- classify: parity groups (wave-aggregated atomics) + pixel->point map ----------------
__global__ void classify(const int* __restrict__ coors, int npts,
                         int* __restrict__ grp, int* __restrict__ cnt,
                         int* __restrict__ idx) {
    int t = blockIdx.x * blockDim.x + threadIdx.x;
    int lane = threadIdx.x & 63;
    int g = -1;
    if (t < npts) {
        int b = coors[3 * t], y = coors[3 * t + 1], x = coors[3 * t + 2];
        g = (y & 1) * 2 + (x & 1);
        idx[(b * HH + y) * WW + x] = t;
    }
    #pragma unroll
    for (int gg = 0; gg < 4; ++gg) {
        unsigned long long mask = __ballot(g == gg);
        if (!mask) continue;
        int leader = __ffsll((long long)mask) - 1;
        int base = 0;
        if (lane == leader) base = atomicAdd(&cnt[gg], __popcll(mask));
        base = __shfl(base, leader);
        if (g == gg) {
            int rank = __popcll(mask & ((1ULL << lane) - 1ULL));
            grp[gg * npts + base + rank] = t;
        }
    }
}

// ---------------- conv1: 3x3 stride-2 VALID, bf16 MFMA, two-phase LDS gather-staging ----------------
// block: 32 j x 128 co (4 waves, wave w -> co pair {2w, 2w+1} of 16-col groups, all 32 j).
// Stage: phase A dedup idx lookups (198 pixels), phase B 16B-granule row gathers from featsB.
__global__ __launch_bounds__(256, 4) void conv1_mfma(const unsigned short* __restrict__ featsB,
                                                     const int* __restrict__ idxm,
                                                     const unsigned short* __restrict__ W1p,
                                                     unsigned short* __restrict__ mid, int npts) {
    __shared__ unsigned short lds[3 * 66 * 64];  // 25,344 B
    __shared__ int ids[200];
    const int j0 = blockIdx.x * 32;
    const int i  = blockIdx.y;
    const int b  = blockIdx.z;
    const int tid = threadIdx.x;
    const int w = tid >> 6, l = tid & 63;

    // phase A: one idx lookup per pixel (rows 2i..2i+2, x = 2*j0 .. 2*j0+65)
    if (tid < 198) {
        int r = tid / 66, xx = tid - r * 66;
        int gx = 2 * j0 + xx;
        int id = npts;
        if (gx < WW) {
            int v = idxm[(b * HH + 2 * i + r) * WW + gx];
            if (v >= 0) id = v;
        }
        ids[tid] = id;
    }
    __syncthreads();

    // phase B: gather 16B slices; 8 consecutive lanes fetch one full 128B row
    for (int t = tid; t < 1584; t += 256) {
        int pix = t >> 3, c8 = t & 7;
        int r = pix / 66, xx = pix - r * 66;
        ushort8 v = *(const ushort8*)&featsB[(long)ids[pix] * 64 + c8 * 8];
        int sidx = (r * 66 + xx) * 64 + ((c8 ^ ((xx >> 1) & 7)) << 3);
        *(ushort8*)&lds[sidx] = v;
    }
    __syncthreads();

    const int pj0 = l & 15;
    const int hi8 = (l >> 4) * 8;
    f32x4 zf = {0.f, 0.f, 0.f, 0.f};
    f32x4 acc[2][2] = {{zf, zf}, {zf, zf}};

    for (int ky = 0; ky < 3; ++ky) {
        for (int kx = 0; kx < 3; ++kx) {
            const int tap = ky * 3 + kx;
            #pragma unroll
            for (int kc = 0; kc < 2; ++kc) {
                int fo = (((tap * 2 + kc) * 8 + 2 * w) << 9) + l * 8;
                short8 b0 = *(const short8*)&W1p[fo];
                short8 b1 = *(const short8*)&W1p[fo + 512];
                #pragma unroll
                for (int mt = 0; mt < 2; ++mt) {
                    int pj = pj0 + mt * 16;
                    int xx = 2 * pj + kx;
                    int idx2 = ((ky * 66 + xx) * 64 + kc * 32 + hi8) ^ (((xx >> 1) & 7) << 3);
                    short8 a = *(const short8*)&lds[idx2];
                    acc[mt][0] = __builtin_amdgcn_mfma_f32_16x16x32_bf16(a, b0, acc[mt][0], 0, 0, 0);
                    acc[mt][1] = __builtin_amdgcn_mfma_f32_16x16x32_bf16(a, b1, acc[mt][1], 0, 0, 0);
                }
            }
        }
    }

    // epilogue: D col = l&15 -> co, row = (l>>4)*4+reg -> j (m89-verified layout)
    const int n0 = 32 * w + (l & 15);
    const int rowbase = (l >> 4) * 4;
    #pragma unroll
    for (int mt = 0; mt < 2; ++mt) {
        #pragma unroll
        for (int reg = 0; reg < 4; ++reg) {
            int j = j0 + mt * 16 + rowbase + reg;
            if (j < WO) {
                long base = (((long)b * HO + i) * WO + j) * COUTC;
                mid[base + n0]      = f2bf(acc[mt][0][reg]);
                mid[base + n0 + 16] = f2bf(acc[mt][1][reg]);
            }
        }
    }
}

// ---------------- conv2: parity-grouped masked deconv via bf16 MFMA gather-GEMM ----------------
// block = 128 points x 64 co, 4 waves; wave w: points [32w, 32w+32), all 64 co (2 m-frags).
__global__ __launch_bounds__(256, 4) void conv2_mfma(const unsigned short* __restrict__ mid,
                                                     const unsigned short* __restrict__ W2p,
                                                     const int* __restrict__ coors,
                                                     const int* __restrict__ grp,
                                                     const int* __restrict__ cnt,
                                                     float* __restrict__ res, int npts) {
    __shared__ int meta[128 * 4];

    const int g  = blockIdx.y;
    const int n  = cnt[g];
    const int p0 = blockIdx.x * 128;
    if (p0 >= n) return;
    const int gy = g >> 1, gx = g & 1;
    const int tid = threadIdx.x, l = tid & 63, w = tid >> 6;

    if (tid < 128) {
        int pp = p0 + tid;
        if (pp < n) {
            int t = grp[g * npts + pp];
            meta[tid * 4 + 0] = coors[3 * t + 0];
            meta[tid * 4 + 1] = coors[3 * t + 1];
            meta[tid * 4 + 2] = coors[3 * t + 2];
            meta[tid * 4 + 3] = t;
        } else {
            meta[tid * 4 + 1] = -1;
        }
    }
    __syncthreads();

    const int pbase = w * 32;
    const int hi8 = (l >> 4) * 8;
    int bA[2], yA[2], xA[2];
    #pragma unroll
    for (int mt = 0; mt < 2; ++mt) {
        int pA = pbase + mt * 16 + (l & 15);
        bA[mt] = meta[pA * 4 + 0];
        yA[mt] = meta[pA * 4 + 1];
        xA[mt] = meta[pA * 4 + 2];
    }

    f32x4 zf = {0.f, 0.f, 0.f, 0.f};
    f32x4 acc[2][4];
    #pragma unroll
    for (int mt = 0; mt < 2; ++mt)
        #pragma unroll
        for (int ng = 0; ng < 4; ++ng) acc[mt][ng] = zf;

    const int nsy = gy ? 1 : 2, nsx = gx ? 1 : 2;
    for (int sy = 0; sy < nsy; ++sy) {
        const int ky = gy ? 1 : sy * 2;
        for (int sx = 0; sx < nsx; ++sx) {
            const int kx = gx ? 1 : sx * 2;
            const int tap = ky * 3 + kx;
            long off[2];
            #pragma unroll
            for (int mt = 0; mt < 2; ++mt) {
                int i = gy ? (yA[mt] >> 1) : ((yA[mt] >> 1) - 1 + sy);
                int j = gx ? (xA[mt] >> 1) : ((xA[mt] >> 1) - 1 + sx);
                bool ok = (yA[mt] >= 0) && (unsigned)i < (unsigned)HO && (unsigned)j < (unsigned)WO;
                off[mt] = ok ? ((long)(bA[mt] * HO + i) * WO + j) * COUTC : MIDN;
            }

            #pragma unroll
            for (int kc = 0; kc < 4; ++kc) {
                short8 a0 = *(const short8*)&mid[off[0] + kc * 32 + hi8];
                short8 a1 = *(const short8*)&mid[off[1] + kc * 32 + hi8];
                const unsigned short* wp = &W2p[((tap * 4 + kc) * 4) * 512 + l * 8];
                short8 b0 = *(const short8*)&wp[0];
                short8 b1 = *(const short8*)&wp[512];
                short8 b2 = *(const short8*)&wp[1024];
                short8 b3 = *(const short8*)&wp[1536];
                acc[0][0] = __builtin_amdgcn_mfma_f32_16x16x32_bf16(a0, b0, acc[0][0], 0, 0, 0);
                acc[0][1] = __builtin_amdgcn_mfma_f32_16x16x32_bf16(a0, b1, acc[0][1], 0, 0, 0);
                acc[0][2] = __builtin_amdgcn_mfma_f32_16x16x32_bf16(a0, b2, acc[0][2], 0, 0, 0);
                acc[0][3] = __builtin_amdgcn_mfma_f32_16x16x32_bf16(a0, b3, acc[0][3], 0, 0, 0);
                acc[1][0] = __builtin_amdgcn_mfma_f32_16x16x32_bf16(a1, b0, acc[1][0], 0, 0, 0);
                acc[1][1] = __builtin_amdgcn_mfma_f32_16x16x32_bf16(a1, b1, acc[1][1], 0, 0, 0);
                acc[1][2] = __builtin_amdgcn_mfma_f32_16x16x32_bf16(a1, b2, acc[1][2], 0, 0, 0);
                acc[1][3] = __builtin_amdgcn_mfma_f32_16x16x32_bf16(a1, b3, acc[1][3], 0, 0, 0);
            }
        }
    }

    #pragma unroll
    for (int mt = 0; mt < 2; ++mt) {
        #pragma unroll
        for (int reg = 0; reg < 4; ++reg) {
            int pl = pbase + mt * 16 + (l >> 4) * 4 + reg;
            if (meta[pl * 4 + 1] >= 0) {
                int pt = meta[pl * 4 + 3];
                float* rp = &res[(long)pt * 64 + (l & 15)];
                #pragma unroll
                for (int ng = 0; ng < 4; ++ng) rp[ng * 16] = acc[mt][ng][reg];
            }
        }
    }
}

// ---------------- expand: compact res + idx map -> dense NCHW output (coalesced) ----------------
__global__ __launch_bounds__(256) void expand(const float4* __restrict__ res4,
                                              const int* __restrict__ idx,
                                              float* __restrict__ out) {
    const int y = blockIdx.x, b = blockIdx.y;
    const int tid = threadIdx.x;
    const long plane = (long)HH * WW;
    const int rbase = (b * HH + y) * WW;

    #pragma unroll
    for (int half = 0; half < 2; ++half) {
        int x = half * 256 + tid;
        if (x < WW) {
            int id = idx[rbase + x];
            long obase = (long)b * 64 * plane + (long)y * WW + x;
            #pragma unroll 4
            for (int c4 = 0; c4 < 16; ++c4) {
                float4 v = make_float4(0.f, 0.f, 0.f, 0.f);
                if (id >= 0) v = res4[(long)id * 16 + c4];
                out[obase + (c4 * 4 + 0) * plane] = v.x;
                out[obase + (c4 * 4 + 1) * plane] = v.y;
                out[obase + (c4 * 4 + 2) * plane] = v.z;
                out[obase + (c4 * 4 + 3) * plane] = v.w;
            }
        }
    }
}

extern "C" void kernel_launch(void* const* d_in, const int* in_sizes, int n_in,
                              void* d_out, int out_size, void* d_ws, size_t ws_size,
                              hipStream_t stream) {
    const float* feats = (const float*)d_in[0];
    const int* coors = (const int*)d_in[1];
    const float* W1 = (const float*)d_in[3];
    const float* W2 = (const float*)d_in[4];
    float* out = (float*)d_out;
    int npts = in_sizes[1] / 3;

    // d_ws layout:
    //   midB   MIDN ushorts
    //   zrowB  128 ushorts (zero row adjacent to mid for conv2 OOB gathers)
    //   W1p    73728 ushorts
    //   W2p    73728 ushorts
    //   cnt    4 ints
    //   grp    4*npts ints
    //   idx    NIDX ints
    //   res    npts*64 floats
    //   featsB (npts+1)*64 ushorts (zero row at index npts)
    char* wsb = (char*)d_ws;
    unsigned short* midB  = (unsigned short*)wsb;
    unsigned short* zrowB = midB + MIDN;
    unsigned short* W1p   = zrowB + 128;
    unsigned short* W2p   = W1p + 73728;
    int* cnt = (int*)(W2p + 73728);
    int* grp = cnt + 4;
    int* idx = grp + 4 * npts;
    float* res = (float*)(idx + NIDX);
    unsigned short* featsB = (unsigned short*)(res + (size_t)npts * 64);

    // 1) fused prep
    int pthreads = (npts + 1) * 8;
    prep<<<(pthreads + 255) / 256, 256, 0, stream>>>(feats, W1, W2, featsB, W1p, W2p,
                                                     zrowB, cnt, idx, npts);

    // 2) classify: parity groups + pixel->point map
    classify<<<(npts + 255) / 256, 256, 0, stream>>>(coors, npts, grp, cnt, idx);

    // 3) conv1 via MFMA with two-phase LDS gather-staging -> mid bf16
    conv1_mfma<<<dim3(6, HO, 4), 256, 0, stream>>>(featsB, idx, W1p, midB, npts);

    // 4) conv2 via MFMA -> compact res (indexed by original point id)
    int pblocks = (npts + 127) / 128;
    conv2_mfma<<<dim3(pblocks, 4), 256, 0, stream>>>(midB, W2p, coors, grp, cnt, res, npts);

    // 5) expand compact res to dense NCHW output (writes every element)
    expand<<<dim3(HH, 4), 256, 0, stream>>>((const float4*)res, idx, out);
}